// Round 1
// baseline (139.349 us; speedup 1.0000x reference)
//
#include <hip/hip_runtime.h>
#include <math.h>
#include <stdint.h>

// NetVLAD: N=32, C=512, P=1024, K=64, ALPHA=100. Split-bf16 MFMA.
// R8: R7 pipeline kept verbatim; assign_kernel compute-phase VALU diet:
//  - x staged into LDS as separate hi/lo bf16-pair PLANES (pair-major,
//    [16 pairs][68 cols]) -> compute reads MFMA-ready fragments, no repack.
//  - ssq (x column norms) accumulated in registers from the original f32
//    values during staging (8 fma/chunk) + one LDS tree-reduce at the end,
//    instead of bfhi/bflo reconstruction in the compute phase every chunk.
#define ALPHA 100.0f
#define EPSN 1e-12f

typedef __attribute__((ext_vector_type(8))) short bf16x8;
typedef __attribute__((ext_vector_type(16))) float f32x16;
typedef __attribute__((ext_vector_type(4))) float f32x4;
typedef __attribute__((ext_vector_type(4))) unsigned int u32x4;

static __device__ __forceinline__ uint32_t f2bf(float f) {
    uint32_t u = __builtin_bit_cast(uint32_t, f);
    return (u + 0x7FFFu + ((u >> 16) & 1u)) >> 16;  // RNE
}
static __device__ __forceinline__ float bfhi(uint32_t u) {
    return __builtin_bit_cast(float, u & 0xFFFF0000u);
}
static __device__ __forceinline__ float bflo(uint32_t u) {
    return __builtin_bit_cast(float, u << 16);
}
static __device__ __forceinline__ uint32_t packbf(float a, float b) {
    return f2bf(a) | (f2bf(b) << 16);
}
// CK block_sync_lds(): barrier that waits LDS ops only; global loads
// stay in flight across it (no vmcnt drain).
static __device__ __forceinline__ void lds_barrier() {
    asm volatile("s_waitcnt lgkmcnt(0)\n\ts_barrier" ::: "memory");
}

// ------- prep: v -> (vh, vl) bf16 split [k][c]; bias[k]; zero asum+knorm ----
__global__ __launch_bounds__(64) void prep_kernel(const float* __restrict__ v,
                                                  unsigned short* __restrict__ vh,
                                                  unsigned short* __restrict__ vl,
                                                  float* __restrict__ bias,
                                                  float* __restrict__ az) {
    int k = blockIdx.x, lane = threadIdx.x;
    az[k * 64 + lane] = 0.f;  // 4096 floats = asum(2048) + knorm(2048)
    const float* row = v + k * 512;
    float ssq = 0.f;
#pragma unroll
    for (int i = 0; i < 8; ++i) {
        int c = lane + 64 * i;
        float f = row[c];
        ssq = fmaf(f, f, ssq);
        uint32_t hi = f2bf(f);
        uint32_t lo = f2bf(f - __builtin_bit_cast(float, hi << 16));
        vh[k * 512 + c] = (unsigned short)hi;
        vl[k * 512 + c] = (unsigned short)lo;
    }
#pragma unroll
    for (int off = 32; off > 0; off >>= 1) ssq += __shfl_xor(ssq, off, 64);
    if (lane == 0) bias[k] = -ALPHA * sqrtf(ssq);
}

// ======================= P1 assign helpers ==================================
// Thread (xr = tid>>4, xq = (tid&15)<<2) loads c-rows {c0+2xr, c0+2xr+1},
// cols xq..xq+3 (coalesced: 16 lanes cover one row-pair's 64 cols).
static __device__ __forceinline__ void a_load(float4& pxa, float4& pxb,
                                              u32x4& pvh, u32x4& pvl,
                                              const float* xg,
                                              const unsigned short* vhg,
                                              const unsigned short* vlg,
                                              int c0, int xr, int xq) {
    pxa = *(const float4*)(xg + (size_t)(c0 + 2 * xr) * 1024 + xq);
    pxb = *(const float4*)(xg + (size_t)(c0 + 2 * xr + 1) * 1024 + xq);
    pvh = *(const u32x4*)(vhg + c0);
    pvl = *(const u32x4*)(vlg + c0);
}
// Stage x as hi-plane / lo-plane, pair-major [pair 0..15][68 cols]:
// u32 = bf16(c even) | bf16(c odd)<<16  -> exactly the MFMA B-fragment words.
// One b128 write per plane. ssq accumulated from f32 source values.
static __device__ __forceinline__ void a_stage(uint32_t* xhb, uint32_t* xlb,
                                               uint32_t* vhsb, uint32_t* vlsb,
                                               const float4 pxa, const float4 pxb,
                                               const u32x4 pvh, const u32x4 pvl,
                                               int xr, int xq, int vk, int vj,
                                               f32x4& ssqv) {
    float fa[4] = {pxa.x, pxa.y, pxa.z, pxa.w};
    float fb[4] = {pxb.x, pxb.y, pxb.z, pxb.w};
    u32x4 hp, lp;
#pragma unroll
    for (int i = 0; i < 4; ++i) {
        uint32_t h0 = f2bf(fa[i]);
        uint32_t l0 = f2bf(fa[i] - bfhi(h0 << 16));
        uint32_t h1 = f2bf(fb[i]);
        uint32_t l1 = f2bf(fb[i] - bfhi(h1 << 16));
        hp[i] = h0 | (h1 << 16);
        lp[i] = l0 | (l1 << 16);
        ssqv[i] = fmaf(fa[i], fa[i], fmaf(fb[i], fb[i], ssqv[i]));
    }
    *(u32x4*)&xhb[xr * 68 + xq] = hp;
    *(u32x4*)&xlb[xr * 68 + xq] = lp;
    int vb = vk * 18 + (vj >> 1);
    *(uint2*)&vhsb[vb] = make_uint2(pvh[0], pvh[1]);
    *(uint2*)&vhsb[vb + 2] = make_uint2(pvh[2], pvh[3]);
    *(uint2*)&vlsb[vb] = make_uint2(pvl[0], pvl[1]);
    *(uint2*)&vlsb[vb + 2] = make_uint2(pvl[2], pvl[3]);
}
// Compute: fragments read directly (no repack, no ssq) -> ~8 VALU/chunk.
static __device__ __forceinline__ void a_compute(const uint32_t* xhb,
                                                 const uint32_t* xlb,
                                                 const uint32_t* vhsb,
                                                 const uint32_t* vlsb,
                                                 f32x16& acc,
                                                 int kh, int ph, int h, int cl) {
#pragma unroll
    for (int s = 0; s < 2; ++s) {
        int va = (32 * kh + cl) * 18 + 8 * s + 4 * h;
        uint2 a0 = *(const uint2*)&vhsb[va];
        uint2 a1 = *(const uint2*)&vhsb[va + 2];
        uint2 b0 = *(const uint2*)&vlsb[va];
        uint2 b1 = *(const uint2*)&vlsb[va + 2];
        u32x4 ahp, alp;
        ahp[0] = a0.x; ahp[1] = a0.y; ahp[2] = a1.x; ahp[3] = a1.y;
        alp[0] = b0.x; alp[1] = b0.y; alp[2] = b1.x; alp[3] = b1.y;
        int xb = (8 * s + 4 * h) * 68 + 32 * ph + cl;
        u32x4 bhp, blp;
#pragma unroll
        for (int q = 0; q < 4; ++q) {
            bhp[q] = xhb[xb + q * 68];
            blp[q] = xlb[xb + q * 68];
        }
        bf16x8 ah = __builtin_bit_cast(bf16x8, ahp);
        bf16x8 al = __builtin_bit_cast(bf16x8, alp);
        bf16x8 bh = __builtin_bit_cast(bf16x8, bhp);
        bf16x8 bl = __builtin_bit_cast(bf16x8, blp);
        acc = __builtin_amdgcn_mfma_f32_32x32x16_bf16(ah, bh, acc, 0, 0, 0);
        acc = __builtin_amdgcn_mfma_f32_32x32x16_bf16(ah, bl, acc, 0, 0, 0);
        acc = __builtin_amdgcn_mfma_f32_32x32x16_bf16(al, bh, acc, 0, 0, 0);
    }
}

// ================= P1 assign: D[k][p] = sum_c v[k][c]*x[c][p] ===============
// grid 512 = (n, 64-p block); block 256 = 4 waves (kh,ph), wave 32k x 32p.
__global__ __launch_bounds__(256) void assign_kernel(
    const float* __restrict__ x, const unsigned short* __restrict__ vh,
    const unsigned short* __restrict__ vl, const float* __restrict__ bias,
    unsigned short* __restrict__ aT, float* __restrict__ asum) {
    __shared__ uint32_t xhs[2][16 * 68];
    __shared__ uint32_t xls[2][16 * 68];
    __shared__ uint32_t vhs[2][64 * 18];
    __shared__ uint32_t vls[2][64 * 18];
    __shared__ float bias_l[64];
    __shared__ float xch[2][2][32];
    __shared__ float ssq_s[16 * 68];
    __shared__ float ssq_l[64];

    int tid = threadIdx.x, bx = blockIdx.x;
    int n = bx >> 4, pblk = (bx & 15) << 6;
    int l = tid & 63, w = tid >> 6;
    int kh = w & 1, ph = w >> 1;
    int h = l >> 5, cl = l & 31;

    if (tid < 64) bias_l[tid] = bias[tid];

    int xr = tid >> 4, xq = (tid & 15) << 2;
    int vk = tid >> 2, vj = (tid & 3) << 3;

    const float* xg = x + (size_t)n * 524288 + pblk;
    const unsigned short* vhg = vh + vk * 512 + vj;
    const unsigned short* vlg = vl + vk * 512 + vj;

    f32x16 acc;
#pragma unroll
    for (int r = 0; r < 16; ++r) acc[r] = 0.f;
    f32x4 ssqv;
#pragma unroll
    for (int i = 0; i < 4; ++i) ssqv[i] = 0.f;

    float4 pxa[2], pxb[2];
    u32x4 pvh[2], pvl[2];
    a_load(pxa[0], pxb[0], pvh[0], pvl[0], xg, vhg, vlg, 0, xr, xq);
    a_load(pxa[1], pxb[1], pvh[1], pvl[1], xg, vhg, vlg, 32, xr, xq);
    __syncthreads();  // bias_l visible; one full-drain barrier is fine here
    a_stage(xhs[0], xls[0], vhs[0], vls[0], pxa[0], pxb[0], pvh[0], pvl[0],
            xr, xq, vk, vj, ssqv);
    lds_barrier();
#pragma unroll
    for (int cc = 0; cc < 8; ++cc) {
        // even ch = 2cc: stage ch+1 (set1) -> buf1; load ch+2 -> set0; compute buf0
        a_stage(xhs[1], xls[1], vhs[1], vls[1], pxa[1], pxb[1], pvh[1], pvl[1],
                xr, xq, vk, vj, ssqv);
        if (cc < 7)
            a_load(pxa[0], pxb[0], pvh[0], pvl[0], xg, vhg, vlg, (2 * cc + 2) << 5, xr, xq);
        a_compute(xhs[0], xls[0], vhs[0], vls[0], acc, kh, ph, h, cl);
        lds_barrier();
        // odd ch = 2cc+1: stage ch+2 (set0) -> buf0; load ch+3 -> set1; compute buf1
        if (cc < 7) {
            a_stage(xhs[0], xls[0], vhs[0], vls[0], pxa[0], pxb[0], pvh[0], pvl[0],
                    xr, xq, vk, vj, ssqv);
            a_load(pxa[1], pxb[1], pvh[1], pvl[1], xg, vhg, vlg, (2 * cc + 3) << 5, xr, xq);
        }
        a_compute(xhs[1], xls[1], vhs[1], vls[1], acc, kh, ph, h, cl);
        lds_barrier();
    }
    // ---- epilogue: ssq tree-reduce, then softmax over 64 k per p-col ----
    *(f32x4*)&ssq_s[xr * 68 + xq] = ssqv;
    __syncthreads();
    if (tid < 64) {
        float s = 0.f;
#pragma unroll
        for (int r2 = 0; r2 < 16; ++r2) s += ssq_s[r2 * 68 + tid];
        ssq_l[tid] = s;
    }
    __syncthreads();
    float ssq = ssq_l[32 * ph + cl];
    float sinv = 1.0f / fmaxf(sqrtf(ssq), EPSN);
    float twoAs = 2.0f * ALPHA * sinv;
    float e[16];
    float m = -INFINITY;
#pragma unroll
    for (int r = 0; r < 16; ++r) {
        int k = (r & 3) + 8 * (r >> 2) + 4 * h + 32 * kh;
        float lv = fmaf(twoAs, acc[r], bias_l[k]);
        e[r] = lv;
        m = fmaxf(m, lv);
    }
    m = fmaxf(m, __shfl_xor(m, 32, 64));
    __syncthreads();
    if (l < 32) xch[kh][ph][l] = m;
    __syncthreads();
    m = fmaxf(m, xch[1 - kh][ph][cl]);
    float ssum = 0.f;
#pragma unroll
    for (int r = 0; r < 16; ++r) {
        e[r] = expf(e[r] - m);
        ssum += e[r];
    }
    ssum += __shfl_xor(ssum, 32, 64);
    __syncthreads();
    if (l < 32) xch[kh][ph][l] = ssum;
    __syncthreads();
    ssum += xch[1 - kh][ph][cl];
    float rs = 1.0f / ssum;
    float a2s = rs * sinv;  // a2 = a*sinv (scale folded into a-side)
    unsigned short* aTn = aT + (size_t)n * 65536 + pblk + 32 * ph + cl;
#pragma unroll
    for (int r = 0; r < 16; ++r) {
        int k = (r & 3) + 8 * (r >> 2) + 4 * h + 32 * kh;
        aTn[(size_t)k * 1024] = (unsigned short)f2bf(e[r] * a2s);
        float red = e[r] * rs;
#pragma unroll
        for (int off = 1; off <= 16; off <<= 1) red += __shfl_xor(red, off, 64);
        if (cl == 0) atomicAdd(&asum[n * 64 + k], red);
    }
}

// ======================= P2 vlad helpers ====================================
static __device__ __forceinline__ void v_load(float4& qxa, float4& qxb,
                                              u32x4& qa0, u32x4& qa1,
                                              const float* xg,
                                              const unsigned short* ag, int p0) {
    qxa = *(const float4*)(xg + p0);
    qxb = *(const float4*)(xg + p0 + 32);
    qa0 = *(const u32x4*)(ag + p0);
    qa1 = *(const u32x4*)(ag + p0 + 8);
}
static __device__ __forceinline__ void v_stage(uint32_t* xtb, uint32_t* atb,
                                               const float4 qxa, const float4 qxb,
                                               const u32x4 qa0, const u32x4 qa1,
                                               int xr, int xq, int ak, int aj) {
    int xb = xr * 34 + (xq >> 1);
    *(uint2*)&xtb[xb] = make_uint2(packbf(qxa.x, qxa.y), packbf(qxa.z, qxa.w));
    *(uint2*)&xtb[xb + 16] = make_uint2(packbf(qxb.x, qxb.y), packbf(qxb.z, qxb.w));
    int ab = ak * 34 + (aj >> 1);
    *(uint2*)&atb[ab] = make_uint2(qa0[0], qa0[1]);
    *(uint2*)&atb[ab + 2] = make_uint2(qa0[2], qa0[3]);
    *(uint2*)&atb[ab + 4] = make_uint2(qa1[0], qa1[1]);
    *(uint2*)&atb[ab + 6] = make_uint2(qa1[2], qa1[3]);
}
static __device__ __forceinline__ void v_compute(const uint32_t* xtb,
                                                 const uint32_t* atb,
                                                 f32x16& acc, int kh, int h,
                                                 int cl) {
#pragma unroll
    for (int s = 0; s < 4; ++s) {
        int va = (32 * kh + cl) * 34 + 8 * s + 4 * h;
        uint2 f0 = *(const uint2*)&atb[va];
        uint2 f1 = *(const uint2*)&atb[va + 2];
        int vb = cl * 34 + 8 * s + 4 * h;
        uint2 g0 = *(const uint2*)&xtb[vb];
        uint2 g1 = *(const uint2*)&xtb[vb + 2];
        u32x4 afp, bfp;
        afp[0] = f0.x; afp[1] = f0.y; afp[2] = f1.x; afp[3] = f1.y;
        bfp[0] = g0.x; bfp[1] = g0.y; bfp[2] = g1.x; bfp[3] = g1.y;
        acc = __builtin_amdgcn_mfma_f32_32x32x16_bf16(
            __builtin_bit_cast(bf16x8, afp), __builtin_bit_cast(bf16x8, bfp),
            acc, 0, 0, 0);
    }
}

// ================= P2 vlad: D[k][c] = sum_p a2[k][p]*bf16(x)[c][p] ==========
// grid 512 = (n, 32-c block); block 256 = 4 waves (kh, p-parity).
__global__ __launch_bounds__(256) void vlad_kernel(
    const float* __restrict__ x, const unsigned short* __restrict__ aT,
    const float* __restrict__ asum, const float* __restrict__ vocabs,
    float* __restrict__ out, float* __restrict__ knorm) {
    __shared__ uint32_t xt[2][32 * 34];
    __shared__ uint32_t at[2][64 * 34];
    __shared__ float cmb[2][64][16];
    __shared__ float asum_l[64];

    int tid = threadIdx.x, bx = blockIdx.x;
    int n = bx >> 4, cb = (bx & 15) << 5;
    int l = tid & 63, w = tid >> 6;
    int kh = w & 1, ps = w >> 1;
    int h = l >> 5, cl = l & 31;

    if (tid < 64) asum_l[tid] = asum[n * 64 + tid];

    int xr = tid >> 3, xq = (tid & 7) << 2;
    int ak = tid >> 2, aj = (tid & 3) << 4;

    const float* xg = x + (size_t)n * 524288 + (size_t)(cb + xr) * 1024 + xq;
    const unsigned short* ag = aT + (size_t)n * 65536 + (size_t)ak * 1024 + aj;

    f32x16 acc;
#pragma unroll
    for (int r = 0; r < 16; ++r) acc[r] = 0.f;

    float4 qxa[2], qxb[2];
    u32x4 qa0[2], qa1[2];
    v_load(qxa[0], qxb[0], qa0[0], qa1[0], xg, ag, 0);
    v_load(qxa[1], qxb[1], qa0[1], qa1[1], xg, ag, 64);
    __syncthreads();  // asum_l visible
    v_stage(xt[0], at[0], qxa[0], qxb[0], qa0[0], qa1[0], xr, xq, ak, aj);
    lds_barrier();
#pragma unroll
    for (int cc = 0; cc < 8; ++cc) {
        // even ch = 2cc (computed by ps==0 waves)
        v_stage(xt[1], at[1], qxa[1], qxb[1], qa0[1], qa1[1], xr, xq, ak, aj);
        if (cc < 7)
            v_load(qxa[0], qxb[0], qa0[0], qa1[0], xg, ag, (2 * cc + 2) << 6);
        if (ps == 0) v_compute(xt[0], at[0], acc, kh, h, cl);
        lds_barrier();
        // odd ch = 2cc+1 (computed by ps==1 waves)
        if (cc < 7) {
            v_stage(xt[0], at[0], qxa[0], qxb[0], qa0[0], qa1[0], xr, xq, ak, aj);
            v_load(qxa[1], qxb[1], qa0[1], qa1[1], xg, ag, (2 * cc + 3) << 6);
        }
        if (ps == 1) v_compute(xt[1], at[1], acc, kh, h, cl);
        lds_barrier();
    }
    // ---- epilogue: parity combine, -asum*v, store, knorm (R5 verbatim) ----
    __syncthreads();
    if (ps == 1) {
#pragma unroll
        for (int r = 0; r < 16; ++r) cmb[kh][l][r] = acc[r];
    }
    __syncthreads();
    if (ps == 0) {
#pragma unroll
        for (int r = 0; r < 16; ++r) {
            int k = (r & 3) + 8 * (r >> 2) + 4 * h + 32 * kh;
            int c = cb + cl;
            float val = acc[r] + cmb[kh][l][r];
            val = fmaf(-asum_l[k], vocabs[k * 512 + c], val);
            out[(size_t)n * 32768 + (size_t)k * 512 + c] = val;
            float t2 = val * val;
#pragma unroll
            for (int off = 1; off <= 16; off <<= 1) t2 += __shfl_xor(t2, off, 64);
            if (cl == 0) atomicAdd(&knorm[n * 64 + k], t2);
        }
    }
}

// ---------------- scale: intra-norm (per k) * global norm (per n), in place -
__global__ __launch_bounds__(256) void scale_kernel(float* __restrict__ out,
                                                    const float* __restrict__ knorm) {
    int n = blockIdx.y;
    int sb = blockIdx.x;
    int tid = threadIdx.x;
    __shared__ float sc[64];
    __shared__ float tots;
    if (tid < 64) {
        float kn = knorm[n * 64 + tid];
        float nk = sqrtf(kn);
        float inv = 1.0f / fmaxf(nk, EPSN);
        sc[tid] = inv;
        float t = nk * inv;
        float t2 = t * t;
#pragma unroll
        for (int off = 32; off > 0; off >>= 1) t2 += __shfl_xor(t2, off, 64);
        if (tid == 0) tots = t2;
    }
    __syncthreads();
    float invt = 1.0f / fmaxf(sqrtf(tots), EPSN);
    float* base = out + (size_t)n * 32768 + sb * 4096;
#pragma unroll
    for (int i = 0; i < 16; ++i) {
        int idx = tid + 256 * i;
        int k = (sb * 4096 + idx) >> 9;
        base[idx] *= sc[k] * invt;
    }
}

extern "C" void kernel_launch(void* const* d_in, const int* in_sizes, int n_in,
                              void* d_out, int out_size, void* d_ws, size_t ws_size,
                              hipStream_t stream) {
    const float* x = (const float*)d_in[0];       // [32,512,32,32]
    const float* vocabs = (const float*)d_in[1];  // [64,512]
    float* out = (float*)d_out;                   // [32, 32768]
    char* ws = (char*)d_ws;
    unsigned short* vh = (unsigned short*)(ws);            // 65536 B
    unsigned short* vl = (unsigned short*)(ws + 65536);    // 65536 B
    float* bias  = (float*)(ws + 131072);                  //   256 B
    float* asum  = (float*)(ws + 131328);                  //  8192 B
    float* knorm = (float*)(ws + 139520);                  //  8192 B
    unsigned short* aT = (unsigned short*)(ws + 147712);   // 4 MB : a2 [n][k][p]

    prep_kernel<<<64, 64, 0, stream>>>(vocabs, vh, vl, bias, asum);  // zeroes asum+knorm
    assign_kernel<<<512, 256, 0, stream>>>(x, vh, vl, bias, aT, asum);
    vlad_kernel<<<512, 256, 0, stream>>>(x, aT, asum, vocabs, out, knorm);
    scale_kernel<<<dim3(8, 32), 256, 0, stream>>>(out, knorm);
}